// Round 4
// baseline (68.587 us; speedup 1.0000x reference)
//
#include <hip/hip_runtime.h>
#include <math.h>

#define BB 16
#define PP 16384
#define TT 64
#define CC 85
#define NUMCLS 80
#define WPW 64                         // preds per wave
#define PRED_PER_BLK 256               // 4 waves * 64
#define BLKS_PER_B (PP / PRED_PER_BLK) // 64
#define WSLOTS (PP / WPW)              // 256 slots per batch

typedef float float4u __attribute__((ext_vector_type(4), aligned(4)));

// ws layout (floats):
// [0 .. 2*16*256*64-1]  cand float2[b][slot][t]   (524288 floats = 2 MB)
// [524288 .. 528383]    conf softplus partial per wave-slot (16*256 = 4096)
// [528384 .. 528399]    per-batch partial loss (16)

__global__ __launch_bounds__(256) void pass1_kernel(const float* __restrict__ raw,
                                                    const float* __restrict__ tgt,
                                                    float2* __restrict__ cand,
                                                    float* __restrict__ conf_ws) {
#pragma clang fp contract(off)
    int b     = blockIdx.x >> 6;          // / BLKS_PER_B
    int chunk = blockIdx.x & 63;
    int wave  = threadIdx.x >> 6;
    int lane  = threadIdx.x & 63;
    int p0    = chunk * PRED_PER_BLK + wave * WPW;   // == 64 * slot

    const float* base = raw + (size_t)b * PP * CC;

    __shared__ float4 sbox[4][WPW];       // per-wave slices, no block sync needed
    __shared__ float  sarea[4][WPW];

    // Stage own row: one dwordx4 (4B-aligned ok) + conf scalar.
    {
        const float* pr = base + (size_t)(p0 + lane) * CC;
        float4u bx = *(const float4u*)pr;
        float c = pr[4];
        sbox[wave][lane]  = make_float4(bx.x, bx.y, bx.z, bx.w);
        sarea[wave][lane] = (bx.z - bx.x) * (bx.w - bx.y);
        float conf_acc = fmaxf(c, 0.0f) + log1pf(expf(-fabsf(c)));
        for (int m = 32; m > 0; m >>= 1) conf_acc += __shfl_xor(conf_acc, m);
        if (lane == 0) conf_ws[(size_t)b * WSLOTS + chunk * 4 + wave] = conf_acc;
    }

    // Lane owns target `lane`.
    const float* trow = tgt + (size_t)(b * TT + lane) * 5;
    float tx1 = trow[0], ty1 = trow[1], tx2 = trow[2], ty2 = trow[3];
    float area_t = (tx2 - tx1) * (ty2 - ty1);

    float best = -1.0f;
    int bidx = 0;
#pragma unroll 4
    for (int j = 0; j < WPW; ++j) {
        float4 pb = sbox[wave][j];        // uniform addr -> broadcast
        float ap  = sarea[wave][j];
        float x1 = fmaxf(pb.x, tx1), y1 = fmaxf(pb.y, ty1);
        float x2 = fminf(pb.z, tx2), y2 = fminf(pb.w, ty2);
        float w = x2 - x1, h = y2 - y1;
        float inter = w * h;
        bool valid = (w > 0.0f) && (h > 0.0f);
        float uni = (ap + area_t) - inter;
        float iou = (valid && (uni > 0.0f)) ? (inter / uni) : 0.0f;
        if (iou > best) { best = iou; bidx = p0 + j; }   // ascending j -> first max kept
    }

    int slot = chunk * 4 + wave;          // pred range [64*slot, 64*slot+64)
    cand[((size_t)b * WSLOTS + slot) * TT + lane] = make_float2(best, __int_as_float(bidx));
}

__global__ __launch_bounds__(256) void pass2_kernel(const float* __restrict__ raw,
                                                    const float* __restrict__ tgt,
                                                    const float2* __restrict__ cand,
                                                    const float* __restrict__ conf_ws,
                                                    float* __restrict__ batch_part) {
#pragma clang fp contract(off)
    int b    = blockIdx.x;                // 16 blocks
    int wave = threadIdx.x >> 6;
    int lane = threadIdx.x & 63;

    __shared__ int   sm[TT];
    __shared__ float sacc[4];
    __shared__ float sconf[4];
    __shared__ float ssub;

    float acc = 0.0f;                     // lane0-of-wave accumulator
    const float2* cb0 = cand + (size_t)b * WSLOTS * TT;

    for (int it = 0; it < 16; ++it) {
        int t = wave * 16 + it;
        // argmax over 256 slots for target t
        float v = -2.0f;
        int idx = 0x7fffffff;
        for (int s = lane; s < WSLOTS; s += 64) {
            float2 c2 = cb0[(size_t)s * TT + t];
            int i2 = __float_as_int(c2.y);
            if (c2.x > v || (c2.x == v && i2 < idx)) { v = c2.x; idx = i2; }
        }
        for (int m = 1; m < 64; m <<= 1) {
            float ov = __shfl_xor(v, m);
            int   oi = __shfl_xor(idx, m);
            if (ov > v || (ov == v && oi < idx)) { v = ov; idx = oi; }
        }
        if (lane == 0) sm[t] = idx;

        const float* prow = raw + ((size_t)b * PP + idx) * CC;
        float l0 = prow[5 + lane];
        float l1 = (lane < 16) ? prow[69 + lane] : -INFINITY;
        float mx = fmaxf(l0, l1);
        for (int m = 1; m < 64; m <<= 1) mx = fmaxf(mx, __shfl_xor(mx, m));
        float e = expf(l0 - mx) + ((lane < 16) ? expf(l1 - mx) : 0.0f);
        for (int m = 1; m < 64; m <<= 1) e += __shfl_xor(e, m);

        if (lane == 0) {
            const float* trow = tgt + (size_t)(b * TT + t) * 5;
            int tcls = (int)trow[4];
            float cls = (mx + logf(e)) - prow[5 + tcls];
            float s = 0.0f;
            for (int k = 0; k < 4; ++k) {
                float d = fabsf(prow[k] - trow[k]);
                s += (d < 1.0f) ? 0.5f * d * d : (d - 0.5f);
            }
            acc += 5.0f * s + cls;
        }
    }

    // conf softplus slice: 256 deterministic-order values
    float cf = conf_ws[(size_t)b * WSLOTS + threadIdx.x];
    for (int m = 32; m > 0; m >>= 1) cf += __shfl_xor(cf, m);

    if (lane == 0) { sacc[wave] = acc; sconf[wave] = cf; }
    __syncthreads();

    if (wave == 0) {
        // dedupe matched indices; subtract conf logit for first occurrences
        int m = sm[lane];
        bool first = true;
        for (int t2 = 0; t2 < lane; ++t2)
            if (sm[t2] == m) { first = false; break; }
        float sub = first ? raw[((size_t)b * PP + m) * CC + 4] : 0.0f;
        for (int mm = 32; mm > 0; mm >>= 1) sub += __shfl_xor(sub, mm);
        if (lane == 0) {
            batch_part[b] = ((sacc[0] + sacc[1]) + (sacc[2] + sacc[3]))
                          + ((sconf[0] + sconf[1]) + (sconf[2] + sconf[3])) - sub;
        }
    }
}

__global__ __launch_bounds__(64) void pass3_kernel(const float* __restrict__ batch_part,
                                                   float* __restrict__ out) {
    int lane = threadIdx.x;
    float v = (lane < BB) ? batch_part[lane] : 0.0f;
    for (int m = 32; m > 0; m >>= 1) v += __shfl_xor(v, m);
    if (lane == 0) out[0] = v / (float)BB;
}

extern "C" void kernel_launch(void* const* d_in, const int* in_sizes, int n_in,
                              void* d_out, int out_size, void* d_ws, size_t ws_size,
                              hipStream_t stream) {
    const float* raw = (const float*)d_in[0];
    const float* tgt = (const float*)d_in[1];
    float* out = (float*)d_out;
    float* wsf = (float*)d_ws;

    float2* cand    = (float2*)wsf;                 // 16*256*64 float2
    float*  conf_p  = wsf + 524288;                 // 4096
    float*  bpart   = wsf + 528384;                 // 16

    pass1_kernel<<<BB * BLKS_PER_B, 256, 0, stream>>>(raw, tgt, cand, conf_p);
    pass2_kernel<<<BB, 256, 0, stream>>>(raw, tgt, cand, conf_p, bpart);
    pass3_kernel<<<1, 64, 0, stream>>>(bpart, out);
}

// Round 5
// 53.246 us; speedup vs baseline: 1.2881x; 1.2881x over previous
//
#include <hip/hip_runtime.h>
#include <math.h>

#define BB 16
#define PP 16384
#define TT 64
#define CC 85
#define WPW 64                          // preds per wave
#define PRED_PER_BLK 256                // 4 waves
#define NSLOT 64                        // candidate slots per (b,t) = chunks per batch

typedef float float4u __attribute__((ext_vector_type(4), aligned(4)));

// ws layout (floats):
// [0 .. 131071]      cand float2[bt][slot]   (1024*64 float2 = 512 KB)
// [131072 .. 132095] conf softplus partial per pass1 block (1024)
// [132096 .. 133119] combined 5*box+cls loss per bt (1024)
// [133120 .. 134143] matched idx (int) per bt (1024)

__global__ __launch_bounds__(256) void pass1_kernel(const float* __restrict__ raw,
                                                    const float* __restrict__ tgt,
                                                    float2* __restrict__ cand,
                                                    float* __restrict__ conf_part) {
#pragma clang fp contract(off)
    int b     = blockIdx.x >> 6;           // 16 batches x 64 chunks
    int chunk = blockIdx.x & 63;
    int wave  = threadIdx.x >> 6;
    int lane  = threadIdx.x & 63;
    int p0    = chunk * PRED_PER_BLK + wave * WPW;

    __shared__ float4 sbox[4][WPW];
    __shared__ float  sarea[4][WPW];
    __shared__ float  sval[4][WPW];
    __shared__ int    sidx[4][WPW];
    __shared__ float  sconf[4];

    // Stage own row: one dwordx4 (4B-aligned) + conf scalar. Per-wave slice.
    {
        const float* pr = raw + ((size_t)b * PP + p0 + lane) * CC;
        float4u bx = *(const float4u*)pr;
        float c = pr[4];
        sbox[wave][lane]  = make_float4(bx.x, bx.y, bx.z, bx.w);
        sarea[wave][lane] = (bx.z - bx.x) * (bx.w - bx.y);
        float ca = fmaxf(c, 0.0f) + log1pf(expf(-fabsf(c)));
        for (int m = 32; m > 0; m >>= 1) ca += __shfl_xor(ca, m);
        if (lane == 0) sconf[wave] = ca;
    }

    // Lane owns target `lane`.
    const float* trow = tgt + (size_t)(b * TT + lane) * 5;
    float tx1 = trow[0], ty1 = trow[1], tx2 = trow[2], ty2 = trow[3];
    float area_t = (tx2 - tx1) * (ty2 - ty1);

    float best = -1.0f;
    int bidx = 0;
#pragma unroll 4
    for (int j = 0; j < WPW; ++j) {
        float4 pb = sbox[wave][j];          // uniform addr -> LDS broadcast
        float ap  = sarea[wave][j];
        float x1 = fmaxf(pb.x, tx1), y1 = fmaxf(pb.y, ty1);
        float x2 = fminf(pb.z, tx2), y2 = fminf(pb.w, ty2);
        float w = x2 - x1, h = y2 - y1;
        float inter = w * h;
        bool valid = (w > 0.0f) && (h > 0.0f);
        float uni = (ap + area_t) - inter;
        float iou = (valid && (uni > 0.0f)) ? (inter / uni) : 0.0f;
        if (iou > best) { best = iou; bidx = p0 + j; }   // ascending j -> first max kept
    }
    sval[wave][lane] = best;
    sidx[wave][lane] = bidx;
    __syncthreads();

    if (threadIdx.x == 0)
        conf_part[blockIdx.x] = (sconf[0] + sconf[1]) + (sconf[2] + sconf[3]);

    // Cross-wave reduce (waves cover ascending pred ranges; tie -> lower idx).
    if (wave == 0) {
        float v = sval[0][lane];
        int   i = sidx[0][lane];
        for (int w2 = 1; w2 < 4; ++w2) {
            float v2 = sval[w2][lane];
            int   i2 = sidx[w2][lane];
            if (v2 > v || (v2 == v && i2 < i)) { v = v2; i = i2; }
        }
        // one candidate per (bt, chunk); slot index ascending in pred range
        cand[(size_t)(b * TT + lane) * NSLOT + chunk] = make_float2(v, __int_as_float(i));
    }
}

__global__ __launch_bounds__(64) void pass2_kernel(const float* __restrict__ raw,
                                                   const float* __restrict__ tgt,
                                                   const float2* __restrict__ cand,
                                                   float* __restrict__ loss_bt,
                                                   int* __restrict__ matched) {
#pragma clang fp contract(off)
    int bt = blockIdx.x;                   // 1024 blocks, 1 wave each
    int b = bt >> 6;
    int lane = threadIdx.x;

    // One fully-coalesced 512B read: the 64 slots of this target.
    float2 c2 = cand[(size_t)bt * NSLOT + lane];
    float v = c2.x;
    int idx = __float_as_int(c2.y);
    for (int m = 1; m < 64; m <<= 1) {
        float ov = __shfl_xor(v, m);
        int   oi = __shfl_xor(idx, m);
        if (ov > v || (ov == v && oi < idx)) { v = ov; idx = oi; }
    }
    // all lanes agree on idx now
    const float* prow = raw + ((size_t)b * PP + idx) * CC;
    float l0 = prow[5 + lane];
    float l1 = (lane < 16) ? prow[69 + lane] : -INFINITY;
    float mx = fmaxf(l0, l1);
    for (int m = 1; m < 64; m <<= 1) mx = fmaxf(mx, __shfl_xor(mx, m));
    float e = expf(l0 - mx) + ((lane < 16) ? expf(l1 - mx) : 0.0f);
    for (int m = 1; m < 64; m <<= 1) e += __shfl_xor(e, m);

    if (lane == 0) {
        const float* trow = tgt + (size_t)bt * 5;
        int tcls = (int)trow[4];
        float cls = (mx + logf(e)) - prow[5 + tcls];
        float s = 0.0f;
        for (int k = 0; k < 4; ++k) {
            float d = fabsf(prow[k] - trow[k]);
            s += (d < 1.0f) ? 0.5f * d * d : (d - 0.5f);
        }
        loss_bt[bt] = 5.0f * s + cls;
        matched[bt] = idx;
    }
}

__global__ __launch_bounds__(256) void pass3_kernel(const float* __restrict__ raw,
                                                    const float* __restrict__ conf_part,
                                                    const float* __restrict__ loss_bt,
                                                    const int* __restrict__ matched,
                                                    float* __restrict__ out) {
    __shared__ int sm[BB * TT];
    __shared__ float red[256];
    int tid = threadIdx.x;
    for (int i = tid; i < BB * TT; i += 256) sm[i] = matched[i];
    __syncthreads();

    float acc = 0.0f;
    for (int i = tid; i < BB * TT; i += 256) {
        int m = sm[i];
        bool first = true;
        for (int t2 = i & ~63; t2 < i; ++t2)      // same-batch earlier targets
            if (sm[t2] == m) { first = false; break; }
        int b = i >> 6;
        float sub = first ? raw[((size_t)b * PP + m) * CC + 4] : 0.0f;
        acc += loss_bt[i] - sub;
    }
    for (int i = tid; i < 1024; i += 256) acc += conf_part[i];

    red[tid] = acc;
    __syncthreads();
    for (int s = 128; s > 0; s >>= 1) {
        if (tid < s) red[tid] += red[tid + s];
        __syncthreads();
    }
    if (tid == 0) out[0] = red[0] / (float)BB;
}

extern "C" void kernel_launch(void* const* d_in, const int* in_sizes, int n_in,
                              void* d_out, int out_size, void* d_ws, size_t ws_size,
                              hipStream_t stream) {
    const float* raw = (const float*)d_in[0];
    const float* tgt = (const float*)d_in[1];
    float* out = (float*)d_out;
    float* wsf = (float*)d_ws;

    float2* cand    = (float2*)wsf;                 // 1024*64 float2
    float*  conf_p  = wsf + 131072;                 // 1024
    float*  loss_bt = wsf + 132096;                 // 1024
    int*    match   = (int*)(wsf + 133120);         // 1024

    pass1_kernel<<<BB * 64, 256, 0, stream>>>(raw, tgt, cand, conf_p);
    pass2_kernel<<<BB * TT, 64, 0, stream>>>(raw, tgt, cand, loss_bt, match);
    pass3_kernel<<<1, 256, 0, stream>>>(raw, conf_p, loss_bt, match, out);
}